// Round 13
// baseline (180.231 us; speedup 1.0000x reference)
//
#include <hip/hip_runtime.h>

#define BATCH 4
#define SEQ   2048
#define EMB   128
#define NH    16
#define DK    8

// log2(e) / sqrt(8): fold softmax temperature into exp2 (pre-multiplied into qf)
#define QSCALE 0.510069726f

typedef _Float16 v4h  __attribute__((ext_vector_type(4)));
typedef _Float16 v8h  __attribute__((ext_vector_type(8)));
typedef __fp16   v2fp __attribute__((ext_vector_type(2)));
typedef float    v4f  __attribute__((ext_vector_type(4)));
typedef float    v16f __attribute__((ext_vector_type(16)));

#define CHUNK  512
#define NCH    (SEQ / CHUNK)   // 4
#define VTP    520             // VT col pitch (f16): 260 dwords %32 = 4 -> 2-way max

// ---------------------------------------------------------------------------
// R28 = R27 handoff fusion with ZERO added LDS. R27's 3x regression was an
// occupancy collapse: LDS 35.3 KB/block -> 2 blocks need 70.7 KB > 64 KB
// workgroup-LDS pool -> 1 block/CU -> 2 serial rounds x 1 wave/SIMD
// (VALUBusy/MfmaUtil/Occupancy all fell ~3.2x together -- pure residency
// loss, handoff logic itself innocent: correctness passed). Fix: winner
// waves keep their proj B-frags IN REGISTERS (rt-invariant: 2 col-tiles x
// 8 k-steps = 16 v4h = 32 VGPR, loaded once from L2-hot W with f32->f16
// convert); no Whs LDS at all. Kl/VT back to separate 18.9 KB declarations.
//
// Handoff: proj region rows (b, qg*256..+255) depend on exactly the 16
// head-blocks (b,*,qg). 32 region counters zeroed by block 0 at start
// (first increment ~35us later). Each block: write Ah -> threadfence ->
// syncthreads -> thread0 atomicAdd(cnt[region]); the block drawing old==15
// acquires (threadfence) and projects its whole 256x128 region from L2-hot
// Ah. Deadlock-free (no spinning, any dispatch order).
//
// Layouts (HW-verified): S^T = mfma_32x32x16(A=K, B=Q^T); C/D col=L&31,
// row=(reg&3)+8(reg>>2)+4(L>>5). P=exp2(S^T) packs with pkrtz in natural reg
// order into the PV B-frag PROVIDED V^T is stored with key-index bits 2<->3
// swapped (VT staging perm). qf=0 on half1 kills k=8..15 padding. Ones-row
// d=8 of V^T = softmax denominator; rows 9..31 garbage never stored.
// |score*log2e/sqrt8| <= 4.1 so plain exp is exact. Proj: out = Ah * W^T,
// W row-major IS the B-fragment source, 16x16x16 MFMA (R22-verified math).
// ---------------------------------------------------------------------------
__launch_bounds__(256, 4)
__global__ void attn_proj_kernel(const float* __restrict__ x,
                                 const float* __restrict__ theta,
                                 const float* __restrict__ W,
                                 float* __restrict__ out,
                                 _Float16* __restrict__ Ah /* [B*S][128] */,
                                 unsigned* __restrict__ cnt /* [32] */) {
  __shared__ __align__(16) _Float16 Kl[CHUNK * 8];   // 8 KB: [key][8 dims]
  __shared__ __align__(16) _Float16 VT[10][VTP];     // 10.2 KB
  __shared__ int s_old;

  const int tid = threadIdx.x;
  const int L   = tid & 63;
  const int ln  = L & 31;
  const int hf  = L >> 5;           // lane half
  const int wv  = tid >> 6;         // wave 0..3
  const int bid = blockIdx.x;
  const int bh  = bid >> 3;         // 64 (b,h)
  const int qg  = bid & 7;          // 256-row q group
  const int b = bh >> 4;
  const int h = bh & 15;

  // zero the 32 region counters early; first increment is ~35us away.
  if (bid == 0 && tid < 32) atomicExch(&cnt[tid], 0u);

  float th[DK];
#pragma unroll
  for (int i = 0; i < DK; ++i) th[i] = theta[i];

  // VT row 8 = ones (denominator; persists across restages), row 9 = 0
  for (int i = tid; i < VTP; i += 256) {
    VT[8][i] = (_Float16)1.0f;
    VT[9][i] = (_Float16)0.0f;
  }

  const int c0 = qg >> 1;           // 512-chunk containing this block's q rows
  const int mrow = (ln < 9) ? ln : 9;   // clamped VT row for PV A-frag
  const float* xb = x + (size_t)b * SEQ * EMB + h * DK;

  float4 pa0, pa1, pb0, pb1;        // prefetched x rows (keys tid, tid+256)
  {
    const float* xp = xb + (size_t)(c0 * CHUNK + tid) * EMB;
    pa0 = *(const float4*)(xp);
    pa1 = *(const float4*)(xp + 4);
    pb0 = *(const float4*)(xp + 256 * EMB);
    pb1 = *(const float4*)(xp + 256 * EMB + 4);
  }

  v8h qf0 = {0, 0, 0, 0, 0, 0, 0, 0};
  v8h qf1 = {0, 0, 0, 0, 0, 0, 0, 0};
  v16f acc0, acc1, zf;
#pragma unroll
  for (int i = 0; i < 16; ++i) { acc0[i] = 0.f; acc1[i] = 0.f; zf[i] = 0.f; }

  for (int cc = 0; cc < NCH; ++cc) {
    if (cc) __syncthreads();

    // ---- stage: features for keys tid, tid+256 (16 B/lane Kl writes) ----
    {
      float r0[8], r1[8];
      r0[0] = __cosf(pa0.x + th[0]);
      r0[1] = r0[0] * __cosf(pa0.y + th[1]);
      r0[2] = r0[1] * __cosf(pa0.z + th[2]);
      r0[3] = r0[2] * __cosf(pa0.w + th[3]);
      r0[4] = r0[3] * __cosf(pa1.x + th[4]);
      r0[5] = r0[4] * __cosf(pa1.y + th[5]);
      r0[6] = r0[5] * __cosf(pa1.z + th[6]);
      r0[7] = r0[6] * __cosf(pa1.w + th[7]);
      r1[0] = __cosf(pb0.x + th[0]);
      r1[1] = r1[0] * __cosf(pb0.y + th[1]);
      r1[2] = r1[1] * __cosf(pb0.z + th[2]);
      r1[3] = r1[2] * __cosf(pb0.w + th[3]);
      r1[4] = r1[3] * __cosf(pb1.x + th[4]);
      r1[5] = r1[4] * __cosf(pb1.y + th[5]);
      r1[6] = r1[5] * __cosf(pb1.z + th[6]);
      r1[7] = r1[6] * __cosf(pb1.w + th[7]);

      _Float16 h0[8], h1[8];
#pragma unroll
      for (int i = 0; i < 8; ++i) { h0[i] = (_Float16)r0[i]; h1[i] = (_Float16)r1[i]; }

      union { v4h v[2]; float4 f; } u0, u1;
      u0.v[0] = (v4h){h0[0], h0[1], h0[2], h0[3]};
      u0.v[1] = (v4h){h0[4], h0[5], h0[6], h0[7]};
      u1.v[0] = (v4h){h1[0], h1[1], h1[2], h1[3]};
      u1.v[1] = (v4h){h1[4], h1[5], h1[6], h1[7]};
      *(float4*)&Kl[tid * 8]         = u0.f;
      *(float4*)&Kl[(tid + 256) * 8] = u1.f;

      // VT with within-16 slot perm (swap bits 2<->3 of key index)
      const int j0 = tid, j1 = tid + 256;
      const int col0 = (j0 & ~15) | (j0 & 3) | ((j0 & 4) << 1) | ((j0 & 8) >> 1);
      const int col1 = (j1 & ~15) | (j1 & 3) | ((j1 & 4) << 1) | ((j1 & 8) >> 1);
#pragma unroll
      for (int d = 0; d < 8; ++d) {
        VT[d][col0] = h0[d];
        VT[d][col1] = h1[d];
      }
    }
    __syncthreads();

    // prefetch next chunk's x rows (consumed after the compute phase)
    if (cc + 1 < NCH) {
      const int cn = (c0 + cc + 1) & (NCH - 1);
      const float* xp = xb + (size_t)(cn * CHUNK + tid) * EMB;
      pa0 = *(const float4*)(xp);
      pa1 = *(const float4*)(xp + 4);
      pb0 = *(const float4*)(xp + 256 * EMB);
      pb1 = *(const float4*)(xp + 256 * EMB + 4);
    }

    // qf for BOTH chains from Kl on the q-containing chunk (visited first)
    if (cc == 0 && hf == 0) {
      const int ql = (qg & 1) * 256 + wv * 64 + ln;   // local row in chunk c0
      const _Float16 qs = (_Float16)QSCALE;
      const v8h qsc = {qs, qs, qs, qs, qs, qs, qs, qs};
      qf0 = *(const v8h*)&Kl[ql * 8] * qsc;
      qf1 = *(const v8h*)&Kl[(ql + 32) * 8] * qsc;
    }

    // ---- compute: 16 32-key tiles, dual chain, kf 1-deep LDS prefetch ----
    v8h kf = *(const v8h*)&Kl[ln * 8];
#pragma unroll 2
    for (int kb = 0; kb < CHUNK / 32; ++kb) {
      const v8h kf_n = *(const v8h*)&Kl[((((kb + 1) & 15) * 32) + ln) * 8];
      const v16f s0 = __builtin_amdgcn_mfma_f32_32x32x16_f16(kf, qf0, zf, 0, 0, 0);
      const v16f s1 = __builtin_amdgcn_mfma_f32_32x32x16_f16(kf, qf1, zf, 0, 0, 0);
      const v8h vt0 = *(const v8h*)&VT[mrow][kb * 32 + hf * 8];
      const v8h vt1 = *(const v8h*)&VT[mrow][kb * 32 + 16 + hf * 8];
      union { v2fp p[4]; v8h v; } a0, a1, b0, b1;
#pragma unroll
      for (int i = 0; i < 4; ++i) {
        a0.p[i] = __builtin_amdgcn_cvt_pkrtz(
            __builtin_amdgcn_exp2f(s0[2 * i]),
            __builtin_amdgcn_exp2f(s0[2 * i + 1]));
        a1.p[i] = __builtin_amdgcn_cvt_pkrtz(
            __builtin_amdgcn_exp2f(s0[8 + 2 * i]),
            __builtin_amdgcn_exp2f(s0[8 + 2 * i + 1]));
      }
      acc0 = __builtin_amdgcn_mfma_f32_32x32x16_f16(vt0, a0.v, acc0, 0, 0, 0);
      acc0 = __builtin_amdgcn_mfma_f32_32x32x16_f16(vt1, a1.v, acc0, 0, 0, 0);
#pragma unroll
      for (int i = 0; i < 4; ++i) {
        b0.p[i] = __builtin_amdgcn_cvt_pkrtz(
            __builtin_amdgcn_exp2f(s1[2 * i]),
            __builtin_amdgcn_exp2f(s1[2 * i + 1]));
        b1.p[i] = __builtin_amdgcn_cvt_pkrtz(
            __builtin_amdgcn_exp2f(s1[8 + 2 * i]),
            __builtin_amdgcn_exp2f(s1[8 + 2 * i + 1]));
      }
      acc1 = __builtin_amdgcn_mfma_f32_32x32x16_f16(vt0, b0.v, acc1, 0, 0, 0);
      acc1 = __builtin_amdgcn_mfma_f32_32x32x16_f16(vt1, b1.v, acc1, 0, 0, 0);
      kf = kf_n;
    }
  }

  // ---- attn epilogue: normalize both chains, write Ah ----
  // acc C-layout: col=q=L&31, row=(reg&3)+8(reg>>2)+4*hf.
  // half0 regs 0-3 = dims 0-3, reg4 = row 8 = den; half1 regs 0-3 = dims 4-7.
  {
    const int qrow0 = qg * 256 + wv * 64 + ln;
    const float den0 = __shfl(acc0[4], ln, 64);   // from half0 lane ln
    const float inv0 = 1.0f / den0;
    v4h o0 = {(_Float16)(acc0[0] * inv0), (_Float16)(acc0[1] * inv0),
              (_Float16)(acc0[2] * inv0), (_Float16)(acc0[3] * inv0)};
    *(v4h*)(Ah + ((size_t)b * SEQ + qrow0) * EMB + h * DK + hf * 4) = o0;

    const float den1 = __shfl(acc1[4], ln, 64);
    const float inv1 = 1.0f / den1;
    v4h o1 = {(_Float16)(acc1[0] * inv1), (_Float16)(acc1[1] * inv1),
              (_Float16)(acc1[2] * inv1), (_Float16)(acc1[3] * inv1)};
    *(v4h*)(Ah + ((size_t)b * SEQ + qrow0 + 32) * EMB + h * DK + hf * 4) = o1;
  }

  // ---- handoff: release Ah, count arrivals; last of 16 projects region ----
  __threadfence();                     // release: Ah visible device-wide
  __syncthreads();                     // all waves' stores fenced
  if (tid == 0) s_old = (int)atomicAdd(&cnt[b * 8 + qg], 1u);
  __syncthreads();
  if (s_old != 15) return;             // not the last arriver

  __threadfence();                     // acquire: see all 16 heads' Ah
  // ---- proj for region rows R0..R0+255; B-frags in REGISTERS (no LDS) ----
  {
    const int quad = L >> 4;
    const int l16  = L & 15;
    const int coloff = wv * 32;        // wave's 32-col strip
    const size_t R0 = (size_t)b * SEQ + qg * 256;

    // rt-invariant B-fragments: W rows coloff+nt*16+l16, k cols k8*16+quad*4
    v4h bf[2][8];
#pragma unroll
    for (int nt = 0; nt < 2; ++nt)
#pragma unroll
      for (int k8 = 0; k8 < 8; ++k8) {
        const float4 w = *(const float4*)(
            W + (size_t)(coloff + nt * 16 + l16) * EMB + k8 * 16 + quad * 4);
        bf[nt][k8] = (v4h){(_Float16)w.x, (_Float16)w.y,
                           (_Float16)w.z, (_Float16)w.w};
      }

#pragma unroll 2
    for (int rt = 0; rt < 16; ++rt) {
      v4f pacc0 = (v4f){0.f, 0.f, 0.f, 0.f};
      v4f pacc1 = (v4f){0.f, 0.f, 0.f, 0.f};
#pragma unroll
      for (int k8 = 0; k8 < 8; ++k8) {
        const v4h af = *(const v4h*)(Ah + (R0 + rt * 16 + l16) * EMB
                                        + k8 * 16 + quad * 4);
        pacc0 = __builtin_amdgcn_mfma_f32_16x16x16f16(af, bf[0][k8], pacc0, 0, 0, 0);
        pacc1 = __builtin_amdgcn_mfma_f32_16x16x16f16(af, bf[1][k8], pacc1, 0, 0, 0);
      }
#pragma unroll
      for (int r = 0; r < 4; ++r) {
        out[(R0 + rt * 16 + quad * 4 + r) * EMB + coloff + l16]      = pacc0[r];
        out[(R0 + rt * 16 + quad * 4 + r) * EMB + coloff + 16 + l16] = pacc1[r];
      }
    }
  }
}

// ---------------------------------------------------------------------------
extern "C" void kernel_launch(void* const* d_in, const int* in_sizes, int n_in,
                              void* d_out, int out_size, void* d_ws, size_t ws_size,
                              hipStream_t stream) {
  const float* x     = (const float*)d_in[0];  // [4,2048,128]
  const float* theta = (const float*)d_in[1];  // [8]
  const float* w_out = (const float*)d_in[2];  // [128,128]
  float* out = (float*)d_out;                  // [4,2048,128]

  // workspace: Ah [8192][128] f16 (2 MB) | cnt [32] u32 (zeroed in-kernel by
  // block 0; first increment ~35us later)
  _Float16* Ah  = (_Float16*)d_ws;
  unsigned* cnt = (unsigned*)(Ah + (size_t)BATCH * SEQ * EMB);

  // single fused kernel: feat + dual-q attention + last-arriver projection
  attn_proj_kernel<<<dim3(512), dim3(256), 0, stream>>>(x, theta, w_out, out,
                                                        Ah, cnt);
}

// Round 14
// 94.332 us; speedup vs baseline: 1.9106x; 1.9106x over previous
//
#include <hip/hip_runtime.h>

#define BATCH 4
#define SEQ   2048
#define EMB   128
#define NH    16
#define DK    8

// log2(e) / sqrt(8): fold softmax temperature into exp2 (pre-multiplied into qf)
#define QSCALE 0.510069726f

typedef _Float16 v4h  __attribute__((ext_vector_type(4)));
typedef _Float16 v8h  __attribute__((ext_vector_type(8)));
typedef __fp16   v2fp __attribute__((ext_vector_type(2)));
typedef float    v4f  __attribute__((ext_vector_type(4)));
typedef float    v16f __attribute__((ext_vector_type(16)));

#define CHUNK  512
#define NCH    (SEQ / CHUNK)   // 4
#define VTP    520             // VT col pitch (f16): 260 dwords %32 = 4 -> 2-way max

// ---------------------------------------------------------------------------
// R29 = R26 + quad-q per wave (issue-amortization, the only lever that has
// ever paid: dual-q was -4.8us, matching the predicted shared-overhead
// halving). R27/R28 handoff fusion: 3x regression BOTH times, LDS-invariant
// => structure itself toxic (device-scope fences on non-coherent XCDs);
// abandoned. Here: 4 chains/wave with in-block key-half split (R20-verified
// additive combine): wave wv = key-half (wv&1) x q-quad (wv>>1, 4 q-tiles).
// kf/vt/addr/loop now amortized over 4 chains. S-MFMAs pipelined across
// chains (<=2 s-tiles live). VGPR ~145 => launch_bounds(256,2) -- grid 512
// = 2 blocks/CU anyway, relaxed cap costs nothing (avoids R23's squeeze).
// P-combine (20 KB) overlays dead Kl/VT after a barrier.
//
// Layouts (HW-verified): S^T = mfma_32x32x16(A=K, B=Q^T); C/D col=L&31,
// row=(reg&3)+8(reg>>2)+4(L>>5). P=exp2(S^T) packs with pkrtz in natural reg
// order into the PV B-frag PROVIDED V^T is stored with key-index bits 2<->3
// swapped (VT staging perm). qf=0 on half1 kills k=8..15 padding. Ones-row
// d=8 of V^T = softmax denominator; rows 9..31 garbage never stored.
// |score*log2e/sqrt8| <= 4.1 so plain exp is exact.
// ---------------------------------------------------------------------------
__launch_bounds__(256, 2)
__global__ void attn_kernel(const float* __restrict__ x,
                            const float* __restrict__ theta,
                            _Float16* __restrict__ Ah /* [B*S][128] f16 */) {
  // overlay: {Kl 8 KB | VT 10.2 KB} (compute) / P[4][4][5][64] 20 KB (combine)
  __shared__ __align__(16) char smem[20480];
  _Float16* Kl = (_Float16*)smem;
  _Float16 (*VT)[VTP] = (_Float16 (*)[VTP])(smem + 8192);

  const int tid = threadIdx.x;
  const int L   = tid & 63;
  const int ln  = L & 31;
  const int hf  = L >> 5;           // lane half
  const int wv  = tid >> 6;         // wave 0..3
  const int kh  = wv & 1;           // key half
  const int qq  = wv >> 1;          // q-quad (4 q-tiles)
  const int bh  = blockIdx.x >> 3;  // 64 (b,h)
  const int qg  = blockIdx.x & 7;   // 256-row q group
  const int b = bh >> 4;
  const int h = bh & 15;

  float th[DK];
#pragma unroll
  for (int i = 0; i < DK; ++i) th[i] = theta[i];

  // VT row 8 = ones (denominator; persists across restages), row 9 = 0
  for (int i = tid; i < VTP; i += 256) {
    VT[8][i] = (_Float16)1.0f;
    VT[9][i] = (_Float16)0.0f;
  }

  const int c0 = qg >> 1;           // 512-chunk containing this block's q rows
  const int mrow = (ln < 9) ? ln : 9;   // clamped VT row for PV A-frag
  const float* xb = x + (size_t)b * SEQ * EMB + h * DK;

  float4 pa0, pa1, pb0, pb1;        // prefetched x rows (keys tid, tid+256)
  {
    const float* xp = xb + (size_t)(c0 * CHUNK + tid) * EMB;
    pa0 = *(const float4*)(xp);
    pa1 = *(const float4*)(xp + 4);
    pb0 = *(const float4*)(xp + 256 * EMB);
    pb1 = *(const float4*)(xp + 256 * EMB + 4);
  }

  v8h qf0 = {0, 0, 0, 0, 0, 0, 0, 0};
  v8h qf1 = {0, 0, 0, 0, 0, 0, 0, 0};
  v8h qf2 = {0, 0, 0, 0, 0, 0, 0, 0};
  v8h qf3 = {0, 0, 0, 0, 0, 0, 0, 0};
  v16f acc0, acc1, acc2, acc3, zf;
#pragma unroll
  for (int i = 0; i < 16; ++i) {
    acc0[i] = 0.f; acc1[i] = 0.f; acc2[i] = 0.f; acc3[i] = 0.f; zf[i] = 0.f;
  }

  for (int cc = 0; cc < NCH; ++cc) {
    if (cc) __syncthreads();

    // ---- stage: features for keys tid, tid+256 (16 B/lane Kl writes) ----
    {
      float r0[8], r1[8];
      r0[0] = __cosf(pa0.x + th[0]);
      r0[1] = r0[0] * __cosf(pa0.y + th[1]);
      r0[2] = r0[1] * __cosf(pa0.z + th[2]);
      r0[3] = r0[2] * __cosf(pa0.w + th[3]);
      r0[4] = r0[3] * __cosf(pa1.x + th[4]);
      r0[5] = r0[4] * __cosf(pa1.y + th[5]);
      r0[6] = r0[5] * __cosf(pa1.z + th[6]);
      r0[7] = r0[6] * __cosf(pa1.w + th[7]);
      r1[0] = __cosf(pb0.x + th[0]);
      r1[1] = r1[0] * __cosf(pb0.y + th[1]);
      r1[2] = r1[1] * __cosf(pb0.z + th[2]);
      r1[3] = r1[2] * __cosf(pb0.w + th[3]);
      r1[4] = r1[3] * __cosf(pb1.x + th[4]);
      r1[5] = r1[4] * __cosf(pb1.y + th[5]);
      r1[6] = r1[5] * __cosf(pb1.z + th[6]);
      r1[7] = r1[6] * __cosf(pb1.w + th[7]);

      _Float16 h0[8], h1[8];
#pragma unroll
      for (int i = 0; i < 8; ++i) { h0[i] = (_Float16)r0[i]; h1[i] = (_Float16)r1[i]; }

      union { v4h v[2]; float4 f; } u0, u1;
      u0.v[0] = (v4h){h0[0], h0[1], h0[2], h0[3]};
      u0.v[1] = (v4h){h0[4], h0[5], h0[6], h0[7]};
      u1.v[0] = (v4h){h1[0], h1[1], h1[2], h1[3]};
      u1.v[1] = (v4h){h1[4], h1[5], h1[6], h1[7]};
      *(float4*)&Kl[tid * 8]         = u0.f;
      *(float4*)&Kl[(tid + 256) * 8] = u1.f;

      // VT with within-16 slot perm (swap bits 2<->3 of key index)
      const int j0 = tid, j1 = tid + 256;
      const int col0 = (j0 & ~15) | (j0 & 3) | ((j0 & 4) << 1) | ((j0 & 8) >> 1);
      const int col1 = (j1 & ~15) | (j1 & 3) | ((j1 & 4) << 1) | ((j1 & 8) >> 1);
#pragma unroll
      for (int d = 0; d < 8; ++d) {
        VT[d][col0] = h0[d];
        VT[d][col1] = h1[d];
      }
    }
    __syncthreads();

    // prefetch next chunk's x rows (consumed after the compute phase)
    if (cc + 1 < NCH) {
      const int cn = (c0 + cc + 1) & (NCH - 1);
      const float* xp = xb + (size_t)(cn * CHUNK + tid) * EMB;
      pa0 = *(const float4*)(xp);
      pa1 = *(const float4*)(xp + 4);
      pb0 = *(const float4*)(xp + 256 * EMB);
      pb1 = *(const float4*)(xp + 256 * EMB + 4);
    }

    // qf for all FOUR chains from Kl on the q-containing chunk (first visit)
    if (cc == 0 && hf == 0) {
      const int qloc = (qg & 1) * 256 + qq * 128 + ln;  // chain 0 local row
      const _Float16 qs = (_Float16)QSCALE;
      const v8h qsc = {qs, qs, qs, qs, qs, qs, qs, qs};
      qf0 = *(const v8h*)&Kl[(qloc)      * 8] * qsc;
      qf1 = *(const v8h*)&Kl[(qloc + 32) * 8] * qsc;
      qf2 = *(const v8h*)&Kl[(qloc + 64) * 8] * qsc;
      qf3 = *(const v8h*)&Kl[(qloc + 96) * 8] * qsc;
    }

    // ---- compute: 8 32-key tiles (this wave's key half), quad chain ----
    const int tb = kh * 8;            // tile base within chunk
    v8h kf = *(const v8h*)&Kl[((tb)*32 + ln) * 8];
#pragma unroll 2
    for (int kb = 0; kb < 8; ++kb) {
      const int t = tb + kb;
      const v8h kf_n = *(const v8h*)&Kl[((tb + ((kb + 1) & 7)) * 32 + ln) * 8];
      const v8h vt0 = *(const v8h*)&VT[mrow][t * 32 + hf * 8];
      const v8h vt1 = *(const v8h*)&VT[mrow][t * 32 + 16 + hf * 8];
      // S-MFMAs pipelined across chains: <=2 s-tiles live at once
      v16f s_a = __builtin_amdgcn_mfma_f32_32x32x16_f16(kf, qf0, zf, 0, 0, 0);
      v16f s_b = __builtin_amdgcn_mfma_f32_32x32x16_f16(kf, qf1, zf, 0, 0, 0);
      union { v2fp p[4]; v8h v; } p0, p1;
      // chain 0
#pragma unroll
      for (int i = 0; i < 4; ++i) {
        p0.p[i] = __builtin_amdgcn_cvt_pkrtz(
            __builtin_amdgcn_exp2f(s_a[2 * i]),
            __builtin_amdgcn_exp2f(s_a[2 * i + 1]));
        p1.p[i] = __builtin_amdgcn_cvt_pkrtz(
            __builtin_amdgcn_exp2f(s_a[8 + 2 * i]),
            __builtin_amdgcn_exp2f(s_a[8 + 2 * i + 1]));
      }
      acc0 = __builtin_amdgcn_mfma_f32_32x32x16_f16(vt0, p0.v, acc0, 0, 0, 0);
      acc0 = __builtin_amdgcn_mfma_f32_32x32x16_f16(vt1, p1.v, acc0, 0, 0, 0);
      s_a = __builtin_amdgcn_mfma_f32_32x32x16_f16(kf, qf2, zf, 0, 0, 0);
      // chain 1
#pragma unroll
      for (int i = 0; i < 4; ++i) {
        p0.p[i] = __builtin_amdgcn_cvt_pkrtz(
            __builtin_amdgcn_exp2f(s_b[2 * i]),
            __builtin_amdgcn_exp2f(s_b[2 * i + 1]));
        p1.p[i] = __builtin_amdgcn_cvt_pkrtz(
            __builtin_amdgcn_exp2f(s_b[8 + 2 * i]),
            __builtin_amdgcn_exp2f(s_b[8 + 2 * i + 1]));
      }
      acc1 = __builtin_amdgcn_mfma_f32_32x32x16_f16(vt0, p0.v, acc1, 0, 0, 0);
      acc1 = __builtin_amdgcn_mfma_f32_32x32x16_f16(vt1, p1.v, acc1, 0, 0, 0);
      s_b = __builtin_amdgcn_mfma_f32_32x32x16_f16(kf, qf3, zf, 0, 0, 0);
      // chain 2
#pragma unroll
      for (int i = 0; i < 4; ++i) {
        p0.p[i] = __builtin_amdgcn_cvt_pkrtz(
            __builtin_amdgcn_exp2f(s_a[2 * i]),
            __builtin_amdgcn_exp2f(s_a[2 * i + 1]));
        p1.p[i] = __builtin_amdgcn_cvt_pkrtz(
            __builtin_amdgcn_exp2f(s_a[8 + 2 * i]),
            __builtin_amdgcn_exp2f(s_a[8 + 2 * i + 1]));
      }
      acc2 = __builtin_amdgcn_mfma_f32_32x32x16_f16(vt0, p0.v, acc2, 0, 0, 0);
      acc2 = __builtin_amdgcn_mfma_f32_32x32x16_f16(vt1, p1.v, acc2, 0, 0, 0);
      // chain 3
#pragma unroll
      for (int i = 0; i < 4; ++i) {
        p0.p[i] = __builtin_amdgcn_cvt_pkrtz(
            __builtin_amdgcn_exp2f(s_b[2 * i]),
            __builtin_amdgcn_exp2f(s_b[2 * i + 1]));
        p1.p[i] = __builtin_amdgcn_cvt_pkrtz(
            __builtin_amdgcn_exp2f(s_b[8 + 2 * i]),
            __builtin_amdgcn_exp2f(s_b[8 + 2 * i + 1]));
      }
      acc3 = __builtin_amdgcn_mfma_f32_32x32x16_f16(vt0, p0.v, acc3, 0, 0, 0);
      acc3 = __builtin_amdgcn_mfma_f32_32x32x16_f16(vt1, p1.v, acc3, 0, 0, 0);
      kf = kf_n;
    }
  }

  // ---- epilogue: combine key-half partials across the wave pair ----
  // acc C-layout: col=q=L&31, row=(reg&3)+8(reg>>2)+4*hf.
  // half0 regs 0-3 = dims 0-3, reg4 = row 8 = den; half1 regs 0-3 = dims 4-7.
  __syncthreads();                    // Kl/VT dead; reuse as P
  {
    float (*P)[4][5][64] = (float (*)[4][5][64])smem;
#pragma unroll
    for (int r = 0; r < 5; ++r) {
      P[wv][0][r][L] = acc0[r];
      P[wv][1][r][L] = acc1[r];
      P[wv][2][r][L] = acc2[r];
      P[wv][3][r][L] = acc3[r];
    }
    __syncthreads();
    const int q2 = qq * 2;            // base wave of this quad's key-half pair
#pragma unroll
    for (int j = 0; j < 2; ++j) {
      const int c = kh * 2 + j;       // chain handled by this wave
      float sum[4];
#pragma unroll
      for (int r = 0; r < 4; ++r)
        sum[r] = P[q2][c][r][L] + P[q2 + 1][c][r][L];
      const float den = P[q2][c][4][ln] + P[q2 + 1][c][4][ln];
      const float inv = 1.0f / den;
      const int qrow = qg * 256 + (qq * 4 + c) * 32 + ln;
      v4h o = {(_Float16)(sum[0] * inv), (_Float16)(sum[1] * inv),
               (_Float16)(sum[2] * inv), (_Float16)(sum[3] * inv)};
      *(v4h*)(Ah + ((size_t)b * SEQ + qrow) * EMB + h * DK + hf * 4) = o;
    }
  }
}

// ---------------------------------------------------------------------------
// MFMA projection (R22): 32-row x 64-col tiles, grid (256,2) = 512 blocks.
// Waves: 16-row x 32-col strips. Fragment math HW-verified.
// ---------------------------------------------------------------------------
__launch_bounds__(256, 4)
__global__ void proj_kernel(const _Float16* __restrict__ Ah,
                            const float* __restrict__ W,
                            float* __restrict__ out) {
  __shared__ __align__(16) _Float16 Ahs[32][136];
  __shared__ __align__(16) _Float16 Whs[64][136];

  const int tid  = threadIdx.x;
  const int L    = tid & 63;
  const int wv   = tid >> 6;
  const int quad = L >> 4;
  const int ln   = L & 15;
  const int rowbase = blockIdx.x * 32;
  const int colbase = blockIdx.y * 64;

#pragma unroll
  for (int it = 0; it < 2; ++it) {
    const int idx = it * 256 + tid;     // 0..511 = 32 rows x 16 col-chunks
    const int r  = idx >> 4;
    const int c8 = idx & 15;
    *(uint4*)&Ahs[r][c8 * 8] =
        *(const uint4*)(Ah + (size_t)(rowbase + r) * EMB + c8 * 8);
  }
#pragma unroll
  for (int it = 0; it < 8; ++it) {
    const int idx = it * 256 + tid;
    const int n  = idx >> 5;
    const int c4 = idx & 31;
    const float4 w = *(const float4*)(W + (size_t)(colbase + n) * EMB + c4 * 4);
    v4h wh = {(_Float16)w.x, (_Float16)w.y, (_Float16)w.z, (_Float16)w.w};
    *(v4h*)&Whs[n][c4 * 4] = wh;
  }
  __syncthreads();

  const int rowoff = (wv & 1) * 16;
  const int coloff = (wv >> 1) * 32;

  v4f acc[2];
#pragma unroll
  for (int nt = 0; nt < 2; ++nt) acc[nt] = (v4f){0.f, 0.f, 0.f, 0.f};

#pragma unroll
  for (int k8 = 0; k8 < 8; ++k8) {
    const v4h af = *(const v4h*)&Ahs[rowoff + ln][k8 * 16 + quad * 4];
#pragma unroll
    for (int nt = 0; nt < 2; ++nt) {
      const v4h bf = *(const v4h*)&Whs[coloff + nt * 16 + ln][k8 * 16 + quad * 4];
      acc[nt] = __builtin_amdgcn_mfma_f32_16x16x16f16(af, bf, acc[nt], 0, 0, 0);
    }
  }

#pragma unroll
  for (int nt = 0; nt < 2; ++nt) {
    const int col = colbase + coloff + nt * 16 + ln;
#pragma unroll
    for (int r = 0; r < 4; ++r) {
      out[(size_t)(rowbase + rowoff + quad * 4 + r) * EMB + col] = acc[nt][r];
    }
  }
}

// ---------------------------------------------------------------------------
extern "C" void kernel_launch(void* const* d_in, const int* in_sizes, int n_in,
                              void* d_out, int out_size, void* d_ws, size_t ws_size,
                              hipStream_t stream) {
  const float* x     = (const float*)d_in[0];  // [4,2048,128]
  const float* theta = (const float*)d_in[1];  // [8]
  const float* w_out = (const float*)d_in[2];  // [128,128]
  float* out = (float*)d_out;                  // [4,2048,128]

  _Float16* Ah = (_Float16*)d_ws;              // [8192][128] f16 = 2 MB

  // fused features + quad-q attention: 64 bh x 8 q-groups = 512 blocks
  attn_kernel<<<dim3(512), dim3(256), 0, stream>>>(x, theta, Ah);

  // projection: 256 row-tiles x 2 col-tiles = 512 blocks
  proj_kernel<<<dim3((BATCH * SEQ) / 32, 2), dim3(256), 0, stream>>>(Ah, w_out, out);
}

// Round 15
// 93.970 us; speedup vs baseline: 1.9180x; 1.0039x over previous
//
#include <hip/hip_runtime.h>

#define BATCH 4
#define SEQ   2048
#define EMB   128
#define NH    16
#define DK    8

// log2(e) / sqrt(8): fold softmax temperature into exp2 (pre-multiplied into qf)
#define QSCALE 0.510069726f

typedef _Float16 v4h  __attribute__((ext_vector_type(4)));
typedef _Float16 v8h  __attribute__((ext_vector_type(8)));
typedef __fp16   v2fp __attribute__((ext_vector_type(2)));
typedef float    v4f  __attribute__((ext_vector_type(4)));
typedef float    v16f __attribute__((ext_vector_type(16)));

#define CHUNK  512
#define NCH    (SEQ / CHUNK)   // 4
#define VTP    520             // VT col pitch (f16): 260 dwords %32 = 4 -> 2-way max

// ---------------------------------------------------------------------------
// R30 = R26 (session best, 93.7us) + XCD-locality block remap (T1), the one
// catalog technique never tried. R29 quad-q was flat => amortization lever
// exhausted; full attn ledger falsified (occupancy x3, trans x2, ILP x3,
// phases, handoff x2). In R26 the 8 q-group blocks of one (b,h) read the
// SAME 64KB x-slice but sat at consecutive dispatch indices -> round-robin
// across 8 XCDs -> 8 separate L2 fills (FETCH 17.7MB vs ~4.2MB ideal).
// Remap: bh = bid & 63, qg = bid >> 6 -- the 8 q-groups of a bh now share
// dispatch-index mod 8 -> same XCD -> one L2 fill per slice. Bijective,
// correctness-invariant, zero instruction change.
//
// Structure (R26): 512 blocks x 256 thr; block owns 256 q rows of one (b,h);
// each wave owns TWO q-tiles (64 rows), iterates ALL keys in 4 staged
// 512-key chunks; dual-chain inner loop shares kf/vt/addr/loop; features
// staged in-LDS (no feat kernel). Epilogue: per-chain shfl-den normalize.
//
// Layouts (HW-verified): S^T = mfma_32x32x16(A=K, B=Q^T); C/D col=L&31,
// row=(reg&3)+8(reg>>2)+4(L>>5). P=exp2(S^T) packs with pkrtz in natural reg
// order into the PV B-frag PROVIDED V^T is stored with key-index bits 2<->3
// swapped (VT staging perm). qf=0 on half1 kills k=8..15 padding. Ones-row
// d=8 of V^T = softmax denominator; rows 9..31 garbage never stored.
// |score*log2e/sqrt8| <= 4.1 so plain exp is exact.
// ---------------------------------------------------------------------------
__launch_bounds__(256, 4)
__global__ void attn_kernel(const float* __restrict__ x,
                            const float* __restrict__ theta,
                            _Float16* __restrict__ Ah /* [B*S][128] f16 */) {
  __shared__ __align__(16) _Float16 Kl[CHUNK * 8];   // 8 KB: [key][8 dims]
  __shared__ __align__(16) _Float16 VT[10][VTP];     // 10.2 KB: d 0-7, 8=ones, 9=junk

  const int tid = threadIdx.x;
  const int L   = tid & 63;
  const int ln  = L & 31;
  const int hf  = L >> 5;           // lane half
  const int wv  = tid >> 6;         // wave 0..3
  const int bh  = blockIdx.x & 63;  // XCD remap: 8 q-groups of one bh share
  const int qg  = blockIdx.x >> 6;  // dispatch-index mod 8 -> same XCD L2
  const int b = bh >> 4;
  const int h = bh & 15;

  float th[DK];
#pragma unroll
  for (int i = 0; i < DK; ++i) th[i] = theta[i];

  // VT row 8 = ones (denominator; persists across restages), row 9 = 0
  for (int i = tid; i < VTP; i += 256) {
    VT[8][i] = (_Float16)1.0f;
    VT[9][i] = (_Float16)0.0f;
  }

  const int c0 = qg >> 1;           // 512-chunk containing this block's q rows
  const int mrow = (ln < 9) ? ln : 9;   // clamped VT row for PV A-frag
  const float* xb = x + (size_t)b * SEQ * EMB + h * DK;

  float4 pa0, pa1, pb0, pb1;        // prefetched x rows (keys tid, tid+256)
  {
    const float* xp = xb + (size_t)(c0 * CHUNK + tid) * EMB;
    pa0 = *(const float4*)(xp);
    pa1 = *(const float4*)(xp + 4);
    pb0 = *(const float4*)(xp + 256 * EMB);
    pb1 = *(const float4*)(xp + 256 * EMB + 4);
  }

  v8h qf0 = {0, 0, 0, 0, 0, 0, 0, 0};
  v8h qf1 = {0, 0, 0, 0, 0, 0, 0, 0};
  v16f acc0, acc1, zf;
#pragma unroll
  for (int i = 0; i < 16; ++i) { acc0[i] = 0.f; acc1[i] = 0.f; zf[i] = 0.f; }

  for (int cc = 0; cc < NCH; ++cc) {
    if (cc) __syncthreads();

    // ---- stage: features for keys tid, tid+256 (16 B/lane Kl writes) ----
    {
      float r0[8], r1[8];
      r0[0] = __cosf(pa0.x + th[0]);
      r0[1] = r0[0] * __cosf(pa0.y + th[1]);
      r0[2] = r0[1] * __cosf(pa0.z + th[2]);
      r0[3] = r0[2] * __cosf(pa0.w + th[3]);
      r0[4] = r0[3] * __cosf(pa1.x + th[4]);
      r0[5] = r0[4] * __cosf(pa1.y + th[5]);
      r0[6] = r0[5] * __cosf(pa1.z + th[6]);
      r0[7] = r0[6] * __cosf(pa1.w + th[7]);
      r1[0] = __cosf(pb0.x + th[0]);
      r1[1] = r1[0] * __cosf(pb0.y + th[1]);
      r1[2] = r1[1] * __cosf(pb0.z + th[2]);
      r1[3] = r1[2] * __cosf(pb0.w + th[3]);
      r1[4] = r1[3] * __cosf(pb1.x + th[4]);
      r1[5] = r1[4] * __cosf(pb1.y + th[5]);
      r1[6] = r1[5] * __cosf(pb1.z + th[6]);
      r1[7] = r1[6] * __cosf(pb1.w + th[7]);

      _Float16 h0[8], h1[8];
#pragma unroll
      for (int i = 0; i < 8; ++i) { h0[i] = (_Float16)r0[i]; h1[i] = (_Float16)r1[i]; }

      union { v4h v[2]; float4 f; } u0, u1;
      u0.v[0] = (v4h){h0[0], h0[1], h0[2], h0[3]};
      u0.v[1] = (v4h){h0[4], h0[5], h0[6], h0[7]};
      u1.v[0] = (v4h){h1[0], h1[1], h1[2], h1[3]};
      u1.v[1] = (v4h){h1[4], h1[5], h1[6], h1[7]};
      *(float4*)&Kl[tid * 8]         = u0.f;
      *(float4*)&Kl[(tid + 256) * 8] = u1.f;

      // VT with within-16 slot perm (swap bits 2<->3 of key index)
      const int j0 = tid, j1 = tid + 256;
      const int col0 = (j0 & ~15) | (j0 & 3) | ((j0 & 4) << 1) | ((j0 & 8) >> 1);
      const int col1 = (j1 & ~15) | (j1 & 3) | ((j1 & 4) << 1) | ((j1 & 8) >> 1);
#pragma unroll
      for (int d = 0; d < 8; ++d) {
        VT[d][col0] = h0[d];
        VT[d][col1] = h1[d];
      }
    }
    __syncthreads();

    // prefetch next chunk's x rows (consumed after the compute phase)
    if (cc + 1 < NCH) {
      const int cn = (c0 + cc + 1) & (NCH - 1);
      const float* xp = xb + (size_t)(cn * CHUNK + tid) * EMB;
      pa0 = *(const float4*)(xp);
      pa1 = *(const float4*)(xp + 4);
      pb0 = *(const float4*)(xp + 256 * EMB);
      pb1 = *(const float4*)(xp + 256 * EMB + 4);
    }

    // qf for BOTH chains from Kl on the q-containing chunk (visited first)
    if (cc == 0 && hf == 0) {
      const int ql = (qg & 1) * 256 + wv * 64 + ln;   // local row in chunk c0
      const _Float16 qs = (_Float16)QSCALE;
      const v8h qsc = {qs, qs, qs, qs, qs, qs, qs, qs};
      qf0 = *(const v8h*)&Kl[ql * 8] * qsc;
      qf1 = *(const v8h*)&Kl[(ql + 32) * 8] * qsc;
    }

    // ---- compute: 16 32-key tiles, dual chain, kf 1-deep LDS prefetch ----
    v8h kf = *(const v8h*)&Kl[ln * 8];
#pragma unroll 2
    for (int kb = 0; kb < CHUNK / 32; ++kb) {
      const v8h kf_n = *(const v8h*)&Kl[((((kb + 1) & 15) * 32) + ln) * 8];
      const v16f s0 = __builtin_amdgcn_mfma_f32_32x32x16_f16(kf, qf0, zf, 0, 0, 0);
      const v16f s1 = __builtin_amdgcn_mfma_f32_32x32x16_f16(kf, qf1, zf, 0, 0, 0);
      const v8h vt0 = *(const v8h*)&VT[mrow][kb * 32 + hf * 8];
      const v8h vt1 = *(const v8h*)&VT[mrow][kb * 32 + 16 + hf * 8];
      union { v2fp p[4]; v8h v; } a0, a1, b0, b1;
#pragma unroll
      for (int i = 0; i < 4; ++i) {
        a0.p[i] = __builtin_amdgcn_cvt_pkrtz(
            __builtin_amdgcn_exp2f(s0[2 * i]),
            __builtin_amdgcn_exp2f(s0[2 * i + 1]));
        a1.p[i] = __builtin_amdgcn_cvt_pkrtz(
            __builtin_amdgcn_exp2f(s0[8 + 2 * i]),
            __builtin_amdgcn_exp2f(s0[8 + 2 * i + 1]));
      }
      acc0 = __builtin_amdgcn_mfma_f32_32x32x16_f16(vt0, a0.v, acc0, 0, 0, 0);
      acc0 = __builtin_amdgcn_mfma_f32_32x32x16_f16(vt1, a1.v, acc0, 0, 0, 0);
#pragma unroll
      for (int i = 0; i < 4; ++i) {
        b0.p[i] = __builtin_amdgcn_cvt_pkrtz(
            __builtin_amdgcn_exp2f(s1[2 * i]),
            __builtin_amdgcn_exp2f(s1[2 * i + 1]));
        b1.p[i] = __builtin_amdgcn_cvt_pkrtz(
            __builtin_amdgcn_exp2f(s1[8 + 2 * i]),
            __builtin_amdgcn_exp2f(s1[8 + 2 * i + 1]));
      }
      acc1 = __builtin_amdgcn_mfma_f32_32x32x16_f16(vt0, b0.v, acc1, 0, 0, 0);
      acc1 = __builtin_amdgcn_mfma_f32_32x32x16_f16(vt1, b1.v, acc1, 0, 0, 0);
      kf = kf_n;
    }
  }

  // ---- epilogue: normalize both chains (each wave saw ALL keys) ----
  // acc C-layout: col=q=L&31, row=(reg&3)+8(reg>>2)+4*hf.
  // half0 regs 0-3 = dims 0-3, reg4 = row 8 = den; half1 regs 0-3 = dims 4-7.
  {
    const int qrow0 = qg * 256 + wv * 64 + ln;
    const float den0 = __shfl(acc0[4], ln, 64);   // from half0 lane ln
    const float inv0 = 1.0f / den0;
    v4h o0 = {(_Float16)(acc0[0] * inv0), (_Float16)(acc0[1] * inv0),
              (_Float16)(acc0[2] * inv0), (_Float16)(acc0[3] * inv0)};
    *(v4h*)(Ah + ((size_t)b * SEQ + qrow0) * EMB + h * DK + hf * 4) = o0;

    const float den1 = __shfl(acc1[4], ln, 64);
    const float inv1 = 1.0f / den1;
    v4h o1 = {(_Float16)(acc1[0] * inv1), (_Float16)(acc1[1] * inv1),
              (_Float16)(acc1[2] * inv1), (_Float16)(acc1[3] * inv1)};
    *(v4h*)(Ah + ((size_t)b * SEQ + qrow0 + 32) * EMB + h * DK + hf * 4) = o1;
  }
}

// ---------------------------------------------------------------------------
// MFMA projection (R22): 32-row x 64-col tiles, grid (256,2) = 512 blocks.
// Waves: 16-row x 32-col strips. Fragment math HW-verified.
// ---------------------------------------------------------------------------
__launch_bounds__(256, 4)
__global__ void proj_kernel(const _Float16* __restrict__ Ah,
                            const float* __restrict__ W,
                            float* __restrict__ out) {
  __shared__ __align__(16) _Float16 Ahs[32][136];
  __shared__ __align__(16) _Float16 Whs[64][136];

  const int tid  = threadIdx.x;
  const int L    = tid & 63;
  const int wv   = tid >> 6;
  const int quad = L >> 4;
  const int ln   = L & 15;
  const int rowbase = blockIdx.x * 32;
  const int colbase = blockIdx.y * 64;

#pragma unroll
  for (int it = 0; it < 2; ++it) {
    const int idx = it * 256 + tid;     // 0..511 = 32 rows x 16 col-chunks
    const int r  = idx >> 4;
    const int c8 = idx & 15;
    *(uint4*)&Ahs[r][c8 * 8] =
        *(const uint4*)(Ah + (size_t)(rowbase + r) * EMB + c8 * 8);
  }
#pragma unroll
  for (int it = 0; it < 8; ++it) {
    const int idx = it * 256 + tid;
    const int n  = idx >> 5;
    const int c4 = idx & 31;
    const float4 w = *(const float4*)(W + (size_t)(colbase + n) * EMB + c4 * 4);
    v4h wh = {(_Float16)w.x, (_Float16)w.y, (_Float16)w.z, (_Float16)w.w};
    *(v4h*)&Whs[n][c4 * 4] = wh;
  }
  __syncthreads();

  const int rowoff = (wv & 1) * 16;
  const int coloff = (wv >> 1) * 32;

  v4f acc[2];
#pragma unroll
  for (int nt = 0; nt < 2; ++nt) acc[nt] = (v4f){0.f, 0.f, 0.f, 0.f};

#pragma unroll
  for (int k8 = 0; k8 < 8; ++k8) {
    const v4h af = *(const v4h*)&Ahs[rowoff + ln][k8 * 16 + quad * 4];
#pragma unroll
    for (int nt = 0; nt < 2; ++nt) {
      const v4h bf = *(const v4h*)&Whs[coloff + nt * 16 + ln][k8 * 16 + quad * 4];
      acc[nt] = __builtin_amdgcn_mfma_f32_16x16x16f16(af, bf, acc[nt], 0, 0, 0);
    }
  }

#pragma unroll
  for (int nt = 0; nt < 2; ++nt) {
    const int col = colbase + coloff + nt * 16 + ln;
#pragma unroll
    for (int r = 0; r < 4; ++r) {
      out[(size_t)(rowbase + rowoff + quad * 4 + r) * EMB + col] = acc[nt][r];
    }
  }
}

// ---------------------------------------------------------------------------
extern "C" void kernel_launch(void* const* d_in, const int* in_sizes, int n_in,
                              void* d_out, int out_size, void* d_ws, size_t ws_size,
                              hipStream_t stream) {
  const float* x     = (const float*)d_in[0];  // [4,2048,128]
  const float* theta = (const float*)d_in[1];  // [8]
  const float* w_out = (const float*)d_in[2];  // [128,128]
  float* out = (float*)d_out;                  // [4,2048,128]

  _Float16* Ah = (_Float16*)d_ws;              // [8192][128] f16 = 2 MB

  // fused features + dual-q attention: 512 blocks (XCD-remapped indexing)
  attn_kernel<<<dim3(512), dim3(256), 0, stream>>>(x, theta, Ah);

  // projection: 256 row-tiles x 2 col-tiles = 512 blocks
  proj_kernel<<<dim3((BATCH * SEQ) / 32, 2), dim3(256), 0, stream>>>(Ah, w_out, out);
}